// Round 3
// baseline (473.394 us; speedup 1.0000x reference)
//
#include <hip/hip_runtime.h>
#include <hip/hip_bf16.h>
#include <stdint.h>

#define B_ 8
#define L_ 8192
#define C_ 512

typedef short bf16x8 __attribute__((ext_vector_type(8)));
typedef float f32x4 __attribute__((ext_vector_type(4)));

#define GAS(p) ((const __attribute__((address_space(1))) void*)(p))
#define LAS(p) ((__attribute__((address_space(3))) void*)(p))

// ---------------- kernel 1: kv[b][c] = sum_l (k/||k||) * v ----------------
// 2048 blocks x 256 thr; nontemporal streaming (k+v = 268 MB > 256 MB L3;
// cached loads thrash and capped at 2.6 TB/s; nt delivered ~4.1 TB/s in r2).
__global__ __launch_bounds__(256)
void kv_reduce(const float* __restrict__ kin, const float* __restrict__ vin,
               float* __restrict__ kv) {
    const int bi   = blockIdx.x;
    const int b    = bi >> 8;             // 256 blocks per batch
    const int row0 = (bi & 255) * 32;
    const int lane = threadIdx.x & 63;
    const int wave = threadIdx.x >> 6;

    const f32x4* kb = (const f32x4*)(kin + ((size_t)b * L_ + row0) * C_);
    const f32x4* vb = (const f32x4*)(vin + ((size_t)b * L_ + row0) * C_);

    f32x4 acca = {0.f,0.f,0.f,0.f}, accb = {0.f,0.f,0.f,0.f};

    #pragma unroll 1
    for (int it = 0; it < 2; ++it) {
        const int r0 = wave * 8 + it * 4;
        f32x4 ka[4], kc[4], va[4], vc[4];
        #pragma unroll
        for (int j = 0; j < 4; ++j) {
            const f32x4* krow = kb + (size_t)(r0 + j) * (C_/4);
            ka[j] = __builtin_nontemporal_load(krow + lane);
            kc[j] = __builtin_nontemporal_load(krow + 64 + lane);
        }
        #pragma unroll
        for (int j = 0; j < 4; ++j) {
            const f32x4* vrow = vb + (size_t)(r0 + j) * (C_/4);
            va[j] = __builtin_nontemporal_load(vrow + lane);
            vc[j] = __builtin_nontemporal_load(vrow + 64 + lane);
        }
        float ss[4];
        #pragma unroll
        for (int j = 0; j < 4; ++j)
            ss[j] = ka[j][0]*ka[j][0] + ka[j][1]*ka[j][1] + ka[j][2]*ka[j][2] + ka[j][3]*ka[j][3]
                  + kc[j][0]*kc[j][0] + kc[j][1]*kc[j][1] + kc[j][2]*kc[j][2] + kc[j][3]*kc[j][3];
        #pragma unroll
        for (int m = 32; m >= 1; m >>= 1) {
            #pragma unroll
            for (int j = 0; j < 4; ++j) ss[j] += __shfl_xor(ss[j], m);
        }
        #pragma unroll
        for (int j = 0; j < 4; ++j) {
            const float inv = rsqrtf(ss[j]);
            #pragma unroll
            for (int x = 0; x < 4; ++x) {
                acca[x] += ka[j][x] * inv * va[j][x];
                accb[x] += kc[j][x] * inv * vc[j][x];
            }
        }
    }

    __shared__ __align__(16) float red[4][C_];
    ((f32x4*)&red[wave][0])[lane]      = acca;
    ((f32x4*)&red[wave][0])[64 + lane] = accb;
    __syncthreads();
    for (int c = threadIdx.x; c < C_; c += 256) {
        float s = red[0][c] + red[1][c] + red[2][c] + red[3][c];
        atomicAdd(&kv[b * C_ + c], s);
    }
}

// ---------------- kernel 2: Wb[b][o][c] = bf16(kv[b][c] * W[o][c]) --------
__global__ __launch_bounds__(256)
void prep_w(const float* __restrict__ W, const float* __restrict__ kv,
            __hip_bfloat16* __restrict__ Wb) {
    int idx = blockIdx.x * 256 + threadIdx.x;
    int e   = idx << 2;
    int b   = e >> 18;
    int oc  = e & 0x3FFFF;
    int c   = oc & (C_ - 1);
    float4 w4 = *(const float4*)(W + oc);
    float4 s4 = *(const float4*)(kv + b * C_ + c);
    union { __hip_bfloat16 h[4]; uint2 u; } pk;
    pk.h[0] = __float2bfloat16(w4.x * s4.x);
    pk.h[1] = __float2bfloat16(w4.y * s4.y);
    pk.h[2] = __float2bfloat16(w4.z * s4.z);
    pk.h[3] = __float2bfloat16(w4.w * s4.w);
    *(uint2*)(Wb + e) = pk.u;
}

// ---------------- kernel 3: out = (1/||q_m||) * (q @ Wb^T) + bias ---------
// M=65536, N=512, K=512. BM=BN=128, BK=64, 256 thr = 2x2 waves of 64x64.
// Double-buffered LDS + 2-phase software pipeline (T3 minimum recipe):
// iteration t issues tile t+1's loads (B: global_load_lds; A: fp32->regs)
// BEFORE tile t's ds_read+MFMA, writes A(t+1) to the back buffer after MFMA,
// one barrier per tile. r2 evidence: stage/compute fully serialized
// (MfmaUtil 13%, VALU 17%, hbm 26% -- all idle).
// LDS XOR-swizzle: element (row, k) at row*64 + ((k>>3)^(row&7))*8 + (k&7).
__global__ __launch_bounds__(256, 2)
void gemm_out(const float* __restrict__ qin, const __hip_bfloat16* __restrict__ Wb,
              const float* __restrict__ bias, float* __restrict__ out) {
    const int blk   = blockIdx.x;
    const int xcd   = blk & 7;            // dispatch round-robins XCDs
    const int local = blk >> 3;           // 0..255 within this XCD
    const int n0    = (local & 3) * 128;
    const int m0    = (xcd * 64 + (local >> 2)) * 128;
    const int b     = m0 >> 13;           // 8192 rows per batch
    const int tid  = threadIdx.x;
    const int lane = tid & 63;
    const int wave = tid >> 6;

    __shared__ __align__(16) unsigned short As[2][128 * 64];
    __shared__ __align__(16) unsigned short Bs[2][128 * 64];
    __shared__ float s_inv[128];

    const int aj  = tid & 7;              // k-chunk (8 bf16) within row
    const int arp = tid >> 3;             // 0..31 : row-in-pass
    const float* qbase = qin + (size_t)m0 * C_;
    const __hip_bfloat16* WbB = Wb + ((size_t)b * C_ + n0) * C_;

    const int r16 = lane & 15;
    const int qd  = lane >> 4;
    const int wm  = wave & 1;
    const int wn  = wave >> 1;

    f32x4 acc[4][4];
    #pragma unroll
    for (int i = 0; i < 4; ++i)
        #pragma unroll
        for (int j = 0; j < 4; ++j)
            acc[i][j] = (f32x4){0.f, 0.f, 0.f, 0.f};

    float ssq[4] = {0.f, 0.f, 0.f, 0.f};
    float4 xa[4], xb[4];                  // in-flight A tile (fp32)

    // ---- staging helpers -------------------------------------------------
    auto stageB = [&](int buf, int kc) {
        #pragma unroll
        for (int i = 0; i < 4; ++i) {
            int cid = i * 256 + wave * 64 + lane;     // 16B chunk id
            int n   = cid >> 3;
            int cj  = cid & 7;
            int kk  = ((cj ^ (n & 7)) << 3);
            const __hip_bfloat16* g = WbB + (size_t)n * C_ + kc + kk;
            __builtin_amdgcn_global_load_lds(GAS(g),
                LAS(&Bs[buf][(i * 256 + wave * 64) * 8]), 16, 0, 0);
        }
    };
    auto loadA = [&](int kc) {
        #pragma unroll
        for (int p = 0; p < 4; ++p) {
            const float* g = qbase + (size_t)(p * 32 + arp) * C_ + kc + aj * 8;
            xa[p] = ((const float4*)g)[0];
            xb[p] = ((const float4*)g)[1];
        }
    };
    auto writeA = [&](int buf) {
        #pragma unroll
        for (int p = 0; p < 4; ++p) {
            int m = p * 32 + arp;
            float4 x0 = xa[p], x1 = xb[p];
            ssq[p] += x0.x*x0.x + x0.y*x0.y + x0.z*x0.z + x0.w*x0.w
                    + x1.x*x1.x + x1.y*x1.y + x1.z*x1.z + x1.w*x1.w;
            union { __hip_bfloat16 h[8]; uint4 u; } pk;
            pk.h[0] = __float2bfloat16(x0.x); pk.h[1] = __float2bfloat16(x0.y);
            pk.h[2] = __float2bfloat16(x0.z); pk.h[3] = __float2bfloat16(x0.w);
            pk.h[4] = __float2bfloat16(x1.x); pk.h[5] = __float2bfloat16(x1.y);
            pk.h[6] = __float2bfloat16(x1.z); pk.h[7] = __float2bfloat16(x1.w);
            *(uint4*)&As[buf][m * 64 + ((aj ^ (m & 7)) << 3)] = pk.u;
        }
    };
    auto compute = [&](int buf) {
        #pragma unroll
        for (int ks = 0; ks < 2; ++ks) {
            bf16x8 af[4], bfr[4];
            #pragma unroll
            for (int t = 0; t < 4; ++t) {
                int m = wm * 64 + t * 16 + r16;
                af[t]  = *(const bf16x8*)&As[buf][m * 64 + (((ks * 4 + qd) ^ (m & 7)) << 3)];
                int n = wn * 64 + t * 16 + r16;
                bfr[t] = *(const bf16x8*)&Bs[buf][n * 64 + (((ks * 4 + qd) ^ (n & 7)) << 3)];
            }
            #pragma unroll
            for (int mt = 0; mt < 4; ++mt)
                #pragma unroll
                for (int nt = 0; nt < 4; ++nt)
                    acc[mt][nt] = __builtin_amdgcn_mfma_f32_16x16x32_bf16(
                        af[mt], bfr[nt], acc[mt][nt], 0, 0, 0);
        }
    };

    // ---- prologue: stage tile 0 into buf 0 ------------------------------
    stageB(0, 0);
    loadA(0);
    writeA(0);
    __syncthreads();            // compiler emits vmcnt(0) lgkmcnt(0) drain

    // ---- pipelined main loop: 1 barrier per K-tile -----------------------
    #pragma unroll
    for (int t = 0; t < 7; ++t) {
        const int cur = t & 1, nxt = cur ^ 1;
        stageB(nxt, (t + 1) * 64);   // in flight across compute
        loadA((t + 1) * 64);         // in flight across compute
        compute(cur);                // 32 MFMAs hide the load latency
        writeA(nxt);                 // cvt+ds_write into back buffer
        __syncthreads();
    }
    compute(1);                      // tile 7 lives in buf 1

    // ---- per-row inverse norm: reduce ssq across the 8 aj-threads per row
    #pragma unroll
    for (int p = 0; p < 4; ++p) {
        float s = ssq[p];
        s += __shfl_xor(s, 1);
        s += __shfl_xor(s, 2);
        s += __shfl_xor(s, 4);
        if (aj == 0) s_inv[p * 32 + arp] = rsqrtf(s);
    }
    __syncthreads();

    // ---- epilogue: scale by inv-norm, add bias, store fp32
    #pragma unroll
    for (int nt = 0; nt < 4; ++nt) {
        int col  = n0 + wn * 64 + nt * 16 + r16;
        float bv = bias[col];
        #pragma unroll
        for (int mt = 0; mt < 4; ++mt) {
            int rl = wm * 64 + mt * 16 + qd * 4;
            float4 inv4 = *(const float4*)&s_inv[rl];
            float* op = out + (size_t)(m0 + rl) * C_ + col;
            op[0]      = acc[mt][nt][0] * inv4.x + bv;
            op[C_]     = acc[mt][nt][1] * inv4.y + bv;
            op[2 * C_] = acc[mt][nt][2] * inv4.z + bv;
            op[3 * C_] = acc[mt][nt][3] * inv4.w + bv;
        }
    }
}

extern "C" void kernel_launch(void* const* d_in, const int* in_sizes, int n_in,
                              void* d_out, int out_size, void* d_ws, size_t ws_size,
                              hipStream_t stream) {
    const float* q    = (const float*)d_in[0];
    const float* k    = (const float*)d_in[1];
    const float* v    = (const float*)d_in[2];
    const float* W    = (const float*)d_in[3];
    const float* bias = (const float*)d_in[4];
    float* out = (float*)d_out;

    float* kv = (float*)d_ws;                                  // 8*512 fp32 = 16 KB
    __hip_bfloat16* Wb = (__hip_bfloat16*)((char*)d_ws + 16384); // 8*512*512 bf16 = 4 MB

    hipMemsetAsync(kv, 0, B_ * C_ * sizeof(float), stream);
    kv_reduce<<<2048, 256, 0, stream>>>(k, v, kv);
    prep_w<<<2048, 256, 0, stream>>>(W, kv, Wb);
    gemm_out<<<2048, 256, 0, stream>>>(q, Wb, bias, out);
}

// Round 4
// 412.923 us; speedup vs baseline: 1.1464x; 1.1464x over previous
//
#include <hip/hip_runtime.h>
#include <hip/hip_bf16.h>
#include <stdint.h>

#define B_ 8
#define L_ 8192
#define C_ 512

typedef short bf16x8 __attribute__((ext_vector_type(8)));
typedef float f32x4 __attribute__((ext_vector_type(4)));

#define GAS(p) ((const __attribute__((address_space(1))) void*)(p))
#define LAS(p) ((__attribute__((address_space(3))) void*)(p))

// ------- kernel 1: kv[b][c] = sum_l (k/||k||)*v   AND   qb = bf16(q/||q||) -------
// 2048 blocks x 256 thr; block = 32 rows of one batch for k,v AND q.
// BW-bound streaming kernel with idle VALU -> q-normalization rides along free-ish.
// nt loads: streams (k+v+q = 402 MB) far exceed the 256 MB L3; cached streaming
// thrashes (measured cap 2.6 TB/s in r0/r1; nt delivered ~4.1 TB/s in r2).
// qb stores are REGULAR (allocate in L3) so gemm's A-fetch hits L3.
__global__ __launch_bounds__(256)
void kv_qnorm(const float* __restrict__ kin, const float* __restrict__ vin,
              const float* __restrict__ qin, float* __restrict__ kv,
              __hip_bfloat16* __restrict__ qb) {
    const int bi   = blockIdx.x;
    const int b    = bi >> 8;             // 256 blocks per batch
    const int row0 = (bi & 255) * 32;
    const int lane = threadIdx.x & 63;
    const int wave = threadIdx.x >> 6;

    const f32x4* kb = (const f32x4*)(kin + ((size_t)b * L_ + row0) * C_);
    const f32x4* vb = (const f32x4*)(vin + ((size_t)b * L_ + row0) * C_);

    f32x4 acca = {0.f,0.f,0.f,0.f}, accb = {0.f,0.f,0.f,0.f};

    // ---- k*v/||k|| accumulation (8 rows/wave, 2 phases of 4) ----
    #pragma unroll 1
    for (int it = 0; it < 2; ++it) {
        const int r0 = wave * 8 + it * 4;
        f32x4 ka[4], kc[4], va[4], vc[4];
        #pragma unroll
        for (int j = 0; j < 4; ++j) {
            const f32x4* krow = kb + (size_t)(r0 + j) * (C_/4);
            ka[j] = __builtin_nontemporal_load(krow + lane);
            kc[j] = __builtin_nontemporal_load(krow + 64 + lane);
        }
        #pragma unroll
        for (int j = 0; j < 4; ++j) {
            const f32x4* vrow = vb + (size_t)(r0 + j) * (C_/4);
            va[j] = __builtin_nontemporal_load(vrow + lane);
            vc[j] = __builtin_nontemporal_load(vrow + 64 + lane);
        }
        float ss[4];
        #pragma unroll
        for (int j = 0; j < 4; ++j)
            ss[j] = ka[j][0]*ka[j][0] + ka[j][1]*ka[j][1] + ka[j][2]*ka[j][2] + ka[j][3]*ka[j][3]
                  + kc[j][0]*kc[j][0] + kc[j][1]*kc[j][1] + kc[j][2]*kc[j][2] + kc[j][3]*kc[j][3];
        #pragma unroll
        for (int m = 32; m >= 1; m >>= 1) {
            #pragma unroll
            for (int j = 0; j < 4; ++j) ss[j] += __shfl_xor(ss[j], m);
        }
        #pragma unroll
        for (int j = 0; j < 4; ++j) {
            const float inv = rsqrtf(ss[j]);
            #pragma unroll
            for (int x = 0; x < 4; ++x) {
                acca[x] += ka[j][x] * inv * va[j][x];
                accb[x] += kc[j][x] * inv * vc[j][x];
            }
        }
    }

    // ---- q row-normalize -> bf16 (8 rows/wave, 2 phases of 4) ----
    const f32x4* qg = (const f32x4*)(qin + ((size_t)b * L_ + row0) * C_);
    __hip_bfloat16* qbo = qb + ((size_t)b * L_ + row0) * C_;
    #pragma unroll 1
    for (int it = 0; it < 2; ++it) {
        const int r0 = wave * 8 + it * 4;
        f32x4 qa[4], qc[4];
        #pragma unroll
        for (int j = 0; j < 4; ++j) {
            const f32x4* qrow = qg + (size_t)(r0 + j) * (C_/4);
            qa[j] = __builtin_nontemporal_load(qrow + lane);
            qc[j] = __builtin_nontemporal_load(qrow + 64 + lane);
        }
        float ss[4];
        #pragma unroll
        for (int j = 0; j < 4; ++j)
            ss[j] = qa[j][0]*qa[j][0] + qa[j][1]*qa[j][1] + qa[j][2]*qa[j][2] + qa[j][3]*qa[j][3]
                  + qc[j][0]*qc[j][0] + qc[j][1]*qc[j][1] + qc[j][2]*qc[j][2] + qc[j][3]*qc[j][3];
        #pragma unroll
        for (int m = 32; m >= 1; m >>= 1) {
            #pragma unroll
            for (int j = 0; j < 4; ++j) ss[j] += __shfl_xor(ss[j], m);
        }
        #pragma unroll
        for (int j = 0; j < 4; ++j) {
            const float inv = rsqrtf(ss[j]);
            union { __hip_bfloat16 h[4]; uint2 u; } p0, p1;
            p0.h[0] = __float2bfloat16(qa[j][0] * inv);
            p0.h[1] = __float2bfloat16(qa[j][1] * inv);
            p0.h[2] = __float2bfloat16(qa[j][2] * inv);
            p0.h[3] = __float2bfloat16(qa[j][3] * inv);
            p1.h[0] = __float2bfloat16(qc[j][0] * inv);
            p1.h[1] = __float2bfloat16(qc[j][1] * inv);
            p1.h[2] = __float2bfloat16(qc[j][2] * inv);
            p1.h[3] = __float2bfloat16(qc[j][3] * inv);
            uint2* dst = (uint2*)(qbo + (size_t)(r0 + j) * C_);
            dst[lane]      = p0.u;
            dst[64 + lane] = p1.u;
        }
    }

    // ---- block-level kv reduction ----
    __shared__ __align__(16) float red[4][C_];
    ((f32x4*)&red[wave][0])[lane]      = acca;
    ((f32x4*)&red[wave][0])[64 + lane] = accb;
    __syncthreads();
    for (int c = threadIdx.x; c < C_; c += 256) {
        float s = red[0][c] + red[1][c] + red[2][c] + red[3][c];
        atomicAdd(&kv[b * C_ + c], s);
    }
}

// ---------------- kernel 2: Wb[b][o][c] = bf16(kv[b][c] * W[o][c]) --------
__global__ __launch_bounds__(256)
void prep_w(const float* __restrict__ W, const float* __restrict__ kv,
            __hip_bfloat16* __restrict__ Wb) {
    int idx = blockIdx.x * 256 + threadIdx.x;
    int e   = idx << 2;
    int b   = e >> 18;
    int oc  = e & 0x3FFFF;
    int c   = oc & (C_ - 1);
    float4 w4 = *(const float4*)(W + oc);
    float4 s4 = *(const float4*)(kv + b * C_ + c);
    union { __hip_bfloat16 h[4]; uint2 u; } pk;
    pk.h[0] = __float2bfloat16(w4.x * s4.x);
    pk.h[1] = __float2bfloat16(w4.y * s4.y);
    pk.h[2] = __float2bfloat16(w4.z * s4.z);
    pk.h[3] = __float2bfloat16(w4.w * s4.w);
    *(uint2*)(Wb + e) = pk.u;
}

// ---------------- kernel 3: out = qb @ Wb^T + bias  (pure bf16 GEMM) ------
// M=65536, N=512, K=512. BM=BN=128, BK=64, 256 thr = 2x2 waves of 64x64.
// Both operands staged via global_load_lds (no reg staging -> no spills, the
// r3 failure mode). Double-buffered LDS, 1 barrier per K-tile; next tile's
// loads are in flight across the current tile's 32 MFMAs (m99-class struct).
// LDS XOR-swizzle via pre-swizzled GLOBAL source + swizzled ds_read
// (global_load_lds dest must stay linear): elem (r,k) at r*64+((k>>3^(r&7))<<3)+(k&7).
// XCD remap: 4 N-blocks of an M-panel land on one XCD (r2: FETCH 267->72 MB).
__global__ __launch_bounds__(256, 2)
void gemm_out(const __hip_bfloat16* __restrict__ qbin, const __hip_bfloat16* __restrict__ Wb,
              const float* __restrict__ bias, float* __restrict__ out) {
    const int blk   = blockIdx.x;
    const int xcd   = blk & 7;
    const int local = blk >> 3;
    const int n0    = (local & 3) * 128;
    const int m0    = (xcd * 64 + (local >> 2)) * 128;
    const int b     = m0 >> 13;
    const int tid  = threadIdx.x;
    const int lane = tid & 63;
    const int wave = tid >> 6;

    __shared__ __align__(16) unsigned short As[2][128 * 64];
    __shared__ __align__(16) unsigned short Bs[2][128 * 64];

    const __hip_bfloat16* Abase = qbin + (size_t)m0 * C_;
    const __hip_bfloat16* Bbase = Wb + ((size_t)b * C_ + n0) * C_;

    const int r16 = lane & 15;
    const int qd  = lane >> 4;
    const int wm  = wave & 1;
    const int wn  = wave >> 1;

    f32x4 acc[4][4];
    #pragma unroll
    for (int i = 0; i < 4; ++i)
        #pragma unroll
        for (int j = 0; j < 4; ++j)
            acc[i][j] = (f32x4){0.f, 0.f, 0.f, 0.f};

    auto stage = [&](int buf, int kc) {
        #pragma unroll
        for (int i = 0; i < 4; ++i) {
            int cid = i * 256 + wave * 64 + lane;     // 16B chunk id, 0..1023
            int r   = cid >> 3;                        // tile row
            int cj  = cid & 7;                         // k-chunk within row
            int kk  = ((cj ^ (r & 7)) << 3);           // pre-swizzled source col
            __builtin_amdgcn_global_load_lds(GAS(Abase + (size_t)r * C_ + kc + kk),
                LAS(&As[buf][(i * 256 + wave * 64) * 8]), 16, 0, 0);
            __builtin_amdgcn_global_load_lds(GAS(Bbase + (size_t)r * C_ + kc + kk),
                LAS(&Bs[buf][(i * 256 + wave * 64) * 8]), 16, 0, 0);
        }
    };
    auto compute = [&](int buf) {
        #pragma unroll
        for (int ks = 0; ks < 2; ++ks) {
            bf16x8 af[4], bfr[4];
            #pragma unroll
            for (int t = 0; t < 4; ++t) {
                int m = wm * 64 + t * 16 + r16;
                af[t]  = *(const bf16x8*)&As[buf][m * 64 + (((ks * 4 + qd) ^ (m & 7)) << 3)];
                int n = wn * 64 + t * 16 + r16;
                bfr[t] = *(const bf16x8*)&Bs[buf][n * 64 + (((ks * 4 + qd) ^ (n & 7)) << 3)];
            }
            #pragma unroll
            for (int mt = 0; mt < 4; ++mt)
                #pragma unroll
                for (int nt = 0; nt < 4; ++nt)
                    acc[mt][nt] = __builtin_amdgcn_mfma_f32_16x16x32_bf16(
                        af[mt], bfr[nt], acc[mt][nt], 0, 0, 0);
        }
    };

    stage(0, 0);
    __syncthreads();                 // drains vmcnt(0): tile 0 resident
    #pragma unroll
    for (int t = 0; t < 7; ++t) {
        stage((t & 1) ^ 1, (t + 1) * 64);   // next tile in flight across MFMAs
        compute(t & 1);
        __syncthreads();             // all reads of cur done + next tile landed
    }
    compute(1);

    // ---- epilogue: add bias, store fp32 ----
    #pragma unroll
    for (int nt = 0; nt < 4; ++nt) {
        int col  = n0 + wn * 64 + nt * 16 + r16;
        float bv = bias[col];
        #pragma unroll
        for (int mt = 0; mt < 4; ++mt) {
            int rl = wm * 64 + mt * 16 + qd * 4;
            float* op = out + (size_t)(m0 + rl) * C_ + col;
            op[0]      = acc[mt][nt][0] + bv;
            op[C_]     = acc[mt][nt][1] + bv;
            op[2 * C_] = acc[mt][nt][2] + bv;
            op[3 * C_] = acc[mt][nt][3] + bv;
        }
    }
}

extern "C" void kernel_launch(void* const* d_in, const int* in_sizes, int n_in,
                              void* d_out, int out_size, void* d_ws, size_t ws_size,
                              hipStream_t stream) {
    const float* q    = (const float*)d_in[0];
    const float* k    = (const float*)d_in[1];
    const float* v    = (const float*)d_in[2];
    const float* W    = (const float*)d_in[3];
    const float* bias = (const float*)d_in[4];
    float* out = (float*)d_out;

    float* kv = (float*)d_ws;                                     // 16 KB
    __hip_bfloat16* Wb = (__hip_bfloat16*)((char*)d_ws + 16384);  // 4 MB
    __hip_bfloat16* qb = (__hip_bfloat16*)((char*)d_ws + 16384 + (size_t)B_ * C_ * C_ * 2); // 64 MB

    hipMemsetAsync(kv, 0, B_ * C_ * sizeof(float), stream);
    kv_qnorm<<<2048, 256, 0, stream>>>(k, v, q, kv, qb);
    prep_w<<<2048, 256, 0, stream>>>(W, kv, Wb);
    gemm_out<<<2048, 256, 0, stream>>>(qb, Wb, bias, out);
}